// Round 9
// baseline (307.756 us; speedup 1.0000x reference)
//
#include <hip/hip_runtime.h>
#include <cstdint>
#include <cstddef>

#define NN 50000
#define NE 800000
#define RREL 5
#define NR (NN * RREL)                 // 250000 (dst,type) keys
#define NB5 ((NR + 255) / 256)         // 977

typedef __attribute__((ext_vector_type(8))) short short8;   // 8 bf16 (4 VGPRs)
typedef __attribute__((ext_vector_type(4))) float f32x4;

static __device__ __forceinline__ float lrelu(float v) { return v > 0.f ? v : 0.01f * v; }

static __device__ __forceinline__ unsigned short f32_bf16_rn(float x) {
    unsigned u = __float_as_uint(x);
    return (unsigned short)((u + 0x7FFFu + ((u >> 16) & 1u)) >> 16);
}

// split 8 f32 (two float4) into bf16 hi + lo (x ~= hi + lo)
static __device__ __forceinline__ void split8v(float4 q0, float4 q1, short8& hi, short8& lo) {
    float v[8] = {q0.x, q0.y, q0.z, q0.w, q1.x, q1.y, q1.z, q1.w};
    #pragma unroll
    for (int j = 0; j < 8; ++j) {
        unsigned short h = f32_bf16_rn(v[j]);
        float hf = __uint_as_float(((unsigned)h) << 16);
        unsigned short l = f32_bf16_rn(v[j] - hf);
        hi[j] = (short)h; lo[j] = (short)l;
    }
}

// ---------------------------------------------------------------------------
// 64x64-tile f32 GEMM (e0 = x @ field_W + field_b, K=128)
// ---------------------------------------------------------------------------
template<int K>
__launch_bounds__(256)
__global__ void gemm_tile(const float* __restrict__ A, int lda,
                          const float* __restrict__ B0,
                          const float* __restrict__ bias,
                          float* __restrict__ C, int M)
{
    __shared__ float As[64][68];
    __shared__ float Bs[64][64];
    const int row0 = blockIdx.x * 64;
    const int t = threadIdx.x;
    const int tx = t & 15, ty = t >> 4;

    float acc[4][4] = {};

    for (int kc = 0; kc < K; kc += 64) {
        {
            int arow = t >> 4, akk = (t & 15) << 2;
            #pragma unroll
            for (int rp = 0; rp < 64; rp += 16) {
                int r = rp + arow, gr = row0 + r;
                float4 v = make_float4(0.f, 0.f, 0.f, 0.f);
                if (gr < M) v = *(const float4*)&A[(size_t)gr * lda + kc + akk];
                As[akk + 0][r] = v.x; As[akk + 1][r] = v.y;
                As[akk + 2][r] = v.z; As[akk + 3][r] = v.w;
            }
        }
        #pragma unroll
        for (int idx = t; idx < 1024; idx += 256) {
            int k = idx >> 4, c4 = (idx & 15) << 2;
            *(float4*)&Bs[k][c4] = *(const float4*)&B0[(size_t)(kc + k) * 64 + c4];
        }
        __syncthreads();

        #pragma unroll 8
        for (int k = 0; k < 64; ++k) {
            float4 av = *(const float4*)&As[k][ty * 4];
            float4 bv = *(const float4*)&Bs[k][tx * 4];
            float ar[4] = {av.x, av.y, av.z, av.w};
            float br[4] = {bv.x, bv.y, bv.z, bv.w};
            #pragma unroll
            for (int i = 0; i < 4; ++i)
                #pragma unroll
                for (int j = 0; j < 4; ++j)
                    acc[i][j] = fmaf(ar[i], br[j], acc[i][j]);
        }
        __syncthreads();
    }

    float bb[4];
    {
        const float* bp = bias + tx * 4;
        bb[0] = bp[0]; bb[1] = bp[1]; bb[2] = bp[2]; bb[3] = bp[3];
    }
    #pragma unroll
    for (int i = 0; i < 4; ++i) {
        int gr = row0 + ty * 4 + i;
        if (gr >= M) continue;
        *(float4*)&C[(size_t)gr * 64 + tx * 4] =
            make_float4(acc[i][0] + bb[0], acc[i][1] + bb[1],
                        acc[i][2] + bb[2], acc[i][3] + bb[3]);
    }
}

// ---------------------------------------------------------------------------
// zgather v2: one wave per dst node; type-grouped CSR -> no per-edge selects.
//   segment (n,r) = epack[offs5[n*5+r] .. offs5[n*5+r+1])
//   Z[n][r*64+lane] = sum w*E[src][lane];  S[n*5+r] = sum w
// ---------------------------------------------------------------------------
__launch_bounds__(256)
__global__ void zgather(const int* __restrict__ offs5, const uint2* __restrict__ epack,
                        const float* __restrict__ Eprev,
                        float* __restrict__ Z, float* __restrict__ S)
{
    int wid = (blockIdx.x * 256 + threadIdx.x) >> 6;
    int lane = threadIdx.x & 63;
    if (wid >= NN) return;
    const int b = wid * RREL;
    int cur = offs5[b];
    float* zr = Z + (size_t)wid * 320 + lane;

    #pragma unroll
    for (int r = 0; r < RREL; ++r) {
        int end = offs5[b + r + 1];
        float acc = 0.f, acc2 = 0.f, sv = 0.f;
        int p = cur;
        for (; p + 2 <= end; p += 2) {
            uint2 qa = epack[p], qb = epack[p + 1];
            float va = Eprev[((size_t)(qa.x << 6)) + lane];
            float vb = Eprev[((size_t)(qb.x << 6)) + lane];
            float wa = __uint_as_float(qa.y), wb = __uint_as_float(qb.y);
            acc  = fmaf(wa, va, acc);
            acc2 = fmaf(wb, vb, acc2);
            sv += wa + wb;
        }
        if (p < end) {
            uint2 qa = epack[p];
            float wa = __uint_as_float(qa.y);
            acc = fmaf(wa, Eprev[((size_t)(qa.x << 6)) + lane], acc);
            sv += wa;
        }
        zr[r << 6] = acc + acc2;
        if (lane == 0) S[b + r] = sv;
        cur = end;
    }
}

// ---------------------------------------------------------------------------
// prep_wfrag: relW [R][128][64] f32 -> split-bf16 MFMA fragments.
// Chunk c (c<5: Wtop_c, c>=5: Wbot_{c-5}) is 16 KB contiguous:
//   wf[c*1024 + (((s*4+nf)*64 + lane)*2 + h)]  (short8 units, h=0 hi / 1 lo)
// frag elem j = W[s*32 + 8*(lane>>4) + j][nf*16 + (lane&15)]
// ---------------------------------------------------------------------------
__launch_bounds__(256)
__global__ void prep_wfrag(const float* __restrict__ rel1_W, const float* __restrict__ rel2_W,
                           short8* __restrict__ wf1, short8* __restrict__ wf2)
{
    int bid = blockIdx.x;
    int layer = bid / 10, c = bid % 10;
    const float* relW = layer ? rel2_W : rel1_W;
    short8* wf = layer ? wf2 : wf1;
    int t = threadIdx.x;
    for (int sl = t; sl < 512; sl += 256) {
        int rid = sl >> 6, lane = sl & 63;
        int s = rid >> 2, nf = rid & 3;
        int g = lane >> 4, lc = lane & 15;
        int r = (c < 5) ? c : c - 5;
        const float* W = relW + (size_t)r * 8192 + ((c < 5) ? 0 : 4096);
        float v[8];
        #pragma unroll
        for (int j = 0; j < 8; ++j)
            v[j] = W[(size_t)(s * 32 + g * 8 + j) * 64 + nf * 16 + lc];
        float4 q0 = make_float4(v[0], v[1], v[2], v[3]);
        float4 q1 = make_float4(v[4], v[5], v[6], v[7]);
        short8 hi, lo;
        split8v(q0, q1, hi, lo);
        size_t slot = (size_t)c * 1024 + (size_t)((s * 4 + nf) * 64 + lane) * 2;
        wf[slot]     = hi;
        wf[slot + 1] = lo;
    }
}

// ---------------------------------------------------------------------------
// zgemm_mfma: 2-phase LDS pipeline (unchanged from R8).
// ---------------------------------------------------------------------------
__launch_bounds__(512)
__global__ void zgemm_mfma(const float* __restrict__ Z,
                           const float* __restrict__ Eprev,
                           const short8* __restrict__ wf,
                           const float* __restrict__ relb,
                           const float* __restrict__ S,
                           float* __restrict__ Enext, int M)
{
    __shared__ short8 wlds[2][1024];   // 2 x 16 KB

    const int t = threadIdx.x;
    const int wid = t >> 6, lane = t & 63;
    const int lc = lane & 15, lg = lane >> 4;
    const int row0 = blockIdx.x * 128 + wid * 16;

    const int nA = row0 + lc;
    const bool okA = (nA < M);
    const int nodeA = okA ? nA : 0;

    const int sq = t >> 6, sl = t & 63;
    const int wrA = (sq * 2 + 0) * 64 + sl;
    const int wrB = (sq * 2 + 1) * 64 + sl;

    short8 eh[2], el[2];
    #pragma unroll
    for (int s = 0; s < 2; ++s) {
        const float* p = &Eprev[(size_t)nodeA * 64 + s * 32 + lg * 8];
        float4 q0 = okA ? *(const float4*)p       : make_float4(0,0,0,0);
        float4 q1 = okA ? *(const float4*)(p + 4) : make_float4(0,0,0,0);
        split8v(q0, q1, eh[s], el[s]);
    }

    float sD[4][RREL];
    #pragma unroll
    for (int i = 0; i < 4; ++i) {
        int nd = row0 + lg * 4 + i;
        int ns = (nd < M) ? nd : 0;
        #pragma unroll
        for (int r = 0; r < RREL; ++r)
            sD[i][r] = S[(size_t)ns * RREL + r];
    }

    {
        const short8* wp = wf + (size_t)t * 2;
        short8 sa = wp[0], sb = wp[1];
        wlds[0][wrA] = sa; wlds[0][wrB] = sb;
    }
    float4 az0[2], az1[2];
    {
        const float* p0 = &Z[(size_t)nodeA * 320 + 0 * 32 + lg * 8];
        const float* p1 = &Z[(size_t)nodeA * 320 + 1 * 32 + lg * 8];
        az0[0] = okA ? *(const float4*)p0       : make_float4(0,0,0,0);
        az0[1] = okA ? *(const float4*)(p0 + 4) : make_float4(0,0,0,0);
        az1[0] = okA ? *(const float4*)p1       : make_float4(0,0,0,0);
        az1[1] = okA ? *(const float4*)(p1 + 4) : make_float4(0,0,0,0);
    }
    __syncthreads();

    f32x4 acc[4];
    #pragma unroll
    for (int nf = 0; nf < 4; ++nf) acc[nf] = (f32x4){0.f, 0.f, 0.f, 0.f};

    short8 sreg_a, sreg_b;
    float4 pz0[2], pz1[2];

    #pragma unroll
    for (int c = 0; c < 10; ++c) {
        const int cb = c & 1;
        if (c < 9) {
            const short8* wp = wf + (size_t)(c + 1) * 1024 + (size_t)t * 2;
            sreg_a = wp[0]; sreg_b = wp[1];
        }
        if (c < 4) {
            const float* p0 = &Z[(size_t)nodeA * 320 + (c + 1) * 64 + 0 * 32 + lg * 8];
            const float* p1 = &Z[(size_t)nodeA * 320 + (c + 1) * 64 + 1 * 32 + lg * 8];
            pz0[0] = okA ? *(const float4*)p0       : make_float4(0,0,0,0);
            pz0[1] = okA ? *(const float4*)(p0 + 4) : make_float4(0,0,0,0);
            pz1[0] = okA ? *(const float4*)p1       : make_float4(0,0,0,0);
            pz1[1] = okA ? *(const float4*)(p1 + 4) : make_float4(0,0,0,0);
        }

        short8 Ah[2], Al[2];
        if (c < 5) {
            split8v(az0[0], az0[1], Ah[0], Al[0]);
            split8v(az1[0], az1[1], Ah[1], Al[1]);
        } else {
            Ah[0] = eh[0]; Al[0] = el[0];
            Ah[1] = eh[1]; Al[1] = el[1];
        }

        if (c < 5) {
            #pragma unroll
            for (int s = 0; s < 2; ++s)
                #pragma unroll
                for (int nf = 0; nf < 4; ++nf) {
                    short8 bh = wlds[cb][((s * 4 + nf) * 2 + 0) * 64 + lane];
                    short8 bl = wlds[cb][((s * 4 + nf) * 2 + 1) * 64 + lane];
                    acc[nf] = __builtin_amdgcn_mfma_f32_16x16x32_bf16(Ah[s], bh, acc[nf], 0, 0, 0);
                    acc[nf] = __builtin_amdgcn_mfma_f32_16x16x32_bf16(Al[s], bh, acc[nf], 0, 0, 0);
                    acc[nf] = __builtin_amdgcn_mfma_f32_16x16x32_bf16(Ah[s], bl, acc[nf], 0, 0, 0);
                }
        } else {
            f32x4 tmp[4];
            #pragma unroll
            for (int nf = 0; nf < 4; ++nf) tmp[nf] = (f32x4){0.f, 0.f, 0.f, 0.f};
            #pragma unroll
            for (int s = 0; s < 2; ++s)
                #pragma unroll
                for (int nf = 0; nf < 4; ++nf) {
                    short8 bh = wlds[cb][((s * 4 + nf) * 2 + 0) * 64 + lane];
                    short8 bl = wlds[cb][((s * 4 + nf) * 2 + 1) * 64 + lane];
                    tmp[nf] = __builtin_amdgcn_mfma_f32_16x16x32_bf16(Ah[s], bh, tmp[nf], 0, 0, 0);
                    tmp[nf] = __builtin_amdgcn_mfma_f32_16x16x32_bf16(Al[s], bh, tmp[nf], 0, 0, 0);
                    tmp[nf] = __builtin_amdgcn_mfma_f32_16x16x32_bf16(Ah[s], bl, tmp[nf], 0, 0, 0);
                }
            const int r = c - 5;
            #pragma unroll
            for (int nf = 0; nf < 4; ++nf)
                #pragma unroll
                for (int i = 0; i < 4; ++i)
                    acc[nf][i] += sD[i][r] * tmp[nf][i];
        }

        if (c < 4) {
            az0[0] = pz0[0]; az0[1] = pz0[1];
            az1[0] = pz1[0]; az1[1] = pz1[1];
        }

        if (c < 9) {
            __syncthreads();
            wlds[cb ^ 1][wrA] = sreg_a;
            wlds[cb ^ 1][wrB] = sreg_b;
            __syncthreads();
        }
    }

    float bbv[4][RREL];
    #pragma unroll
    for (int nf = 0; nf < 4; ++nf)
        #pragma unroll
        for (int r = 0; r < RREL; ++r)
            bbv[nf][r] = relb[r * 64 + nf * 16 + lc];

    #pragma unroll
    for (int i = 0; i < 4; ++i) {
        int nd = row0 + lg * 4 + i;
        if (nd >= M) continue;
        #pragma unroll
        for (int nf = 0; nf < 4; ++nf) {
            float v = acc[nf][i];
            #pragma unroll
            for (int r = 0; r < RREL; ++r)
                v += sD[i][r] * bbv[nf][r];
            Enext[(size_t)nd * 64 + nf * 16 + lc] = v;
        }
    }
}

// ---------------------------------------------------------------------------
// Fused output head: out = sum_s lrelu(Es @ Ws + bs)
// ---------------------------------------------------------------------------
__launch_bounds__(256)
__global__ void head_fused(const float* __restrict__ E0, const float* __restrict__ E1,
                           const float* __restrict__ E2,
                           const float* __restrict__ W0, const float* __restrict__ W1,
                           const float* __restrict__ W2,
                           const float* __restrict__ b0, const float* __restrict__ b1,
                           const float* __restrict__ b2,
                           float* __restrict__ out, int M)
{
    __shared__ float As[64][68];
    __shared__ float Bs[64][64];
    const int row0 = blockIdx.x * 64;
    const int t = threadIdx.x;
    const int tx = t & 15, ty = t >> 4;

    const float* Es[3] = {E0, E1, E2};
    const float* Ws[3] = {W0, W1, W2};
    const float* bs[3] = {b0, b1, b2};

    float acc[4][4] = {};

    #pragma unroll
    for (int s = 0; s < 3; ++s) {
        __syncthreads();
        {
            int arow = t >> 4, akk = (t & 15) << 2;
            #pragma unroll
            for (int rp = 0; rp < 64; rp += 16) {
                int r = rp + arow, gr = row0 + r;
                float4 v = make_float4(0.f, 0.f, 0.f, 0.f);
                if (gr < M) v = *(const float4*)&Es[s][(size_t)gr * 64 + akk];
                As[akk + 0][r] = v.x; As[akk + 1][r] = v.y;
                As[akk + 2][r] = v.z; As[akk + 3][r] = v.w;
            }
        }
        #pragma unroll
        for (int idx = t; idx < 1024; idx += 256) {
            int k = idx >> 4, c4 = (idx & 15) << 2;
            *(float4*)&Bs[k][c4] = *(const float4*)&Ws[s][(size_t)k * 64 + c4];
        }
        __syncthreads();

        float tmp[4][4] = {};
        #pragma unroll 8
        for (int k = 0; k < 64; ++k) {
            float4 av = *(const float4*)&As[k][ty * 4];
            float4 bv = *(const float4*)&Bs[k][tx * 4];
            float ar[4] = {av.x, av.y, av.z, av.w};
            float br[4] = {bv.x, bv.y, bv.z, bv.w};
            #pragma unroll
            for (int i = 0; i < 4; ++i)
                #pragma unroll
                for (int j = 0; j < 4; ++j)
                    tmp[i][j] = fmaf(ar[i], br[j], tmp[i][j]);
        }
        float bb[4];
        {
            const float* bp = bs[s] + tx * 4;
            bb[0] = bp[0]; bb[1] = bp[1]; bb[2] = bp[2]; bb[3] = bp[3];
        }
        #pragma unroll
        for (int i = 0; i < 4; ++i)
            #pragma unroll
            for (int j = 0; j < 4; ++j)
                acc[i][j] += lrelu(tmp[i][j] + bb[j]);
    }

    #pragma unroll
    for (int i = 0; i < 4; ++i) {
        int gr = row0 + ty * 4 + i;
        if (gr >= M) continue;
        *(float4*)&out[(size_t)gr * 64 + tx * 4] =
            make_float4(acc[i][0], acc[i][1], acc[i][2], acc[i][3]);
    }
}

// ---------------------------------------------------------------------------
// CSR build over (dst,type) keys
// ---------------------------------------------------------------------------
__launch_bounds__(256)
__global__ void deg5_hist(const int* __restrict__ dst, const int* __restrict__ etype,
                          int* __restrict__ deg5, int* __restrict__ slot5)
{
    int e = blockIdx.x * 256 + threadIdx.x;
    if (e < NE) slot5[e] = atomicAdd(&deg5[dst[e] * RREL + etype[e]], 1);
}

// per-block sums of deg5 -> b1[NB5]
__launch_bounds__(256)
__global__ void b1_reduce(const int* __restrict__ deg5, int* __restrict__ b1)
{
    __shared__ int sh[256];
    int i = blockIdx.x * 256 + threadIdx.x;
    sh[threadIdx.x] = (i < NR) ? deg5[i] : 0;
    __syncthreads();
    for (int s = 128; s > 0; s >>= 1) {
        if (threadIdx.x < s) sh[threadIdx.x] += sh[threadIdx.x + s];
        __syncthreads();
    }
    if (threadIdx.x == 0) b1[blockIdx.x] = sh[0];
}

// single-block sequential exclusive scan of b1[n]
__launch_bounds__(256)
__global__ void scan_seq(int* __restrict__ b1, int n)
{
    __shared__ int sh[256];
    __shared__ int carry;
    if (threadIdx.x == 0) carry = 0;
    __syncthreads();
    for (int base = 0; base < n; base += 256) {
        int i = base + threadIdx.x;
        int v = (i < n) ? b1[i] : 0;
        sh[threadIdx.x] = v;
        __syncthreads();
        for (int off = 1; off < 256; off <<= 1) {
            int x = (threadIdx.x >= off) ? sh[threadIdx.x - off] : 0;
            __syncthreads();
            sh[threadIdx.x] += x;
            __syncthreads();
        }
        int excl = sh[threadIdx.x] - v + carry;
        if (i < n) b1[i] = excl;
        __syncthreads();
        if (threadIdx.x == 255) carry = excl + v;
        __syncthreads();
    }
}

// offs5[i] = exclusive scan of deg5 (+ block offset from b1); offs5[NR] = NE
__launch_bounds__(256)
__global__ void offs5_final(const int* __restrict__ deg5, const int* __restrict__ b1,
                            int* __restrict__ offs5)
{
    __shared__ int sh[256];
    int t = threadIdx.x;
    int i = blockIdx.x * 256 + t;
    int v = (i < NR) ? deg5[i] : 0;
    sh[t] = v;
    __syncthreads();
    for (int off = 1; off < 256; off <<= 1) {
        int x = (t >= off) ? sh[t - off] : 0;
        __syncthreads();
        sh[t] += x;
        __syncthreads();
    }
    int excl = sh[t] - v + b1[blockIdx.x];
    if (i <= NR) offs5[i] = excl;
}

// scatter: epack[offs5[dst*5+r] + slot5[e]] = {src, w}
__launch_bounds__(256)
__global__ void scatter_pass(const int* __restrict__ src, const int* __restrict__ dst,
                             const int* __restrict__ etype,
                             const float* __restrict__ etime,
                             const float* __restrict__ beta,
                             const float* __restrict__ lambda_p,
                             const int* __restrict__ slot5, const int* __restrict__ offs5,
                             uint2* __restrict__ epack)
{
    int e = blockIdx.x * 256 + threadIdx.x;
    if (e >= NE) return;
    float b[12];
    #pragma unroll
    for (int j = 0; j < 12; ++j) b[j] = beta[j];
    const float* et = etime + (size_t)e * 12;
    float4 v0 = *(const float4*)(et);
    float4 v1 = *(const float4*)(et + 4);
    float4 v2 = *(const float4*)(et + 8);
    float logit = v0.x*b[0] + v0.y*b[1] + v0.z*b[2] + v0.w*b[3]
                + v1.x*b[4] + v1.y*b[5] + v1.z*b[6] + v1.w*b[7]
                + v2.x*b[8] + v2.y*b[9] + v2.z*b[10] + v2.w*b[11];
    float we = lambda_p[0] * expf(-logit);
    int p = offs5[dst[e] * RREL + etype[e]] + slot5[e];
    epack[p] = make_uint2((unsigned)src[e], __float_as_uint(we));
}

// ---------------------------------------------------------------------------
extern "C" void kernel_launch(void* const* d_in, const int* in_sizes, int n_in,
                              void* d_out, int out_size, void* d_ws, size_t ws_size,
                              hipStream_t stream)
{
    const float* x        = (const float*)d_in[0];
    const int*   eidx     = (const int*)d_in[1];
    const int*   etype    = (const int*)d_in[2];
    const float* etime    = (const float*)d_in[3];
    const float* lambda_p = (const float*)d_in[4];
    const float* beta     = (const float*)d_in[5];
    const float* field_W  = (const float*)d_in[6];
    const float* field_b  = (const float*)d_in[7];
    const float* rel1_W   = (const float*)d_in[8];
    const float* rel1_b   = (const float*)d_in[9];
    const float* rel2_W   = (const float*)d_in[10];
    const float* rel2_b   = (const float*)d_in[11];
    const float* out0_W   = (const float*)d_in[12];
    const float* out0_b   = (const float*)d_in[13];
    const float* out1_W   = (const float*)d_in[14];
    const float* out1_b   = (const float*)d_in[15];
    const float* out2_W   = (const float*)d_in[16];
    const float* out2_b   = (const float*)d_in[17];
    const int* src = eidx;
    const int* dst = eidx + NE;
    float* out = (float*)d_out;

    char* wsb = (char*)d_ws;
    size_t off = 0;
    auto carve = [&](size_t bytes) -> void* {
        void* p = (void*)(wsb + off);
        off += (bytes + 255) & ~(size_t)255;
        return p;
    };
    int*   deg5   = (int*)carve((size_t)NR * 4);            // 1 MB
    int*   offs5  = (int*)carve((size_t)(NR + 1) * 4);      // 1 MB
    int*   b1     = (int*)carve((size_t)NB5 * 4);
    int*   slot5  = (int*)carve((size_t)NE * 4);            // 3.2 MB
    float* S      = (float*)carve((size_t)NR * 4);          // 1 MB
    uint2* epack  = (uint2*)carve((size_t)NE * 8);          // 6.4 MB
    float* e0     = (float*)carve((size_t)NN * 64 * 4);     // 12.8 MB
    float* e1     = (float*)carve((size_t)NN * 64 * 4);     // 12.8 MB
    float* e2     = (float*)carve((size_t)NN * 64 * 4);     // 12.8 MB
    float* Zb     = (float*)carve((size_t)NN * 320 * 4);    // 64 MB
    short8* wf1   = (short8*)carve((size_t)20 * 16384);     // 320 KB
    short8* wf2   = (short8*)carve((size_t)20 * 16384);     // 320 KB

    dim3 blk(256);
    const int NT64  = (NN + 63) / 64;       // 782
    const int NT128 = (NN + 127) / 128;     // 391
    const int EB = (NE + 255) / 256;
    const int GB = (NN * 64 + 255) / 256;   // one wave per node

    // ---- CSR build over (dst,type) + weight frag prep ----
    hipMemsetAsync(deg5, 0, (size_t)NR * 4, stream);
    deg5_hist<<<EB, blk, 0, stream>>>(dst, etype, deg5, slot5);
    prep_wfrag<<<20, blk, 0, stream>>>(rel1_W, rel2_W, wf1, wf2);
    b1_reduce<<<NB5, blk, 0, stream>>>(deg5, b1);
    scan_seq<<<1, blk, 0, stream>>>(b1, NB5);
    offs5_final<<<NB5, blk, 0, stream>>>(deg5, b1, offs5);
    scatter_pass<<<EB, blk, 0, stream>>>(src, dst, etype, etime, beta, lambda_p,
                                         slot5, offs5, epack);

    // ---- e0 = x @ field_W + field_b ----
    gemm_tile<128><<<dim3(NT64), blk, 0, stream>>>(x, 128, field_W, field_b, e0, NN);

    // ---- layer 1 ----
    zgather<<<GB, blk, 0, stream>>>(offs5, epack, e0, Zb, S);
    zgemm_mfma<<<dim3(NT128), dim3(512), 0, stream>>>(Zb, e0, wf1, rel1_b, S, e1, NN);

    // ---- layer 2 ----
    zgather<<<GB, blk, 0, stream>>>(offs5, epack, e1, Zb, S);
    zgemm_mfma<<<dim3(NT128), dim3(512), 0, stream>>>(Zb, e1, wf2, rel2_b, S, e2, NN);

    // ---- output head (single pass) ----
    head_fused<<<dim3(NT64), blk, 0, stream>>>(e0, e1, e2, out0_W, out1_W, out2_W,
                                               out0_b, out1_b, out2_b, out, NN);
}

// Round 10
// 275.756 us; speedup vs baseline: 1.1160x; 1.1160x over previous
//
#include <hip/hip_runtime.h>
#include <cstdint>
#include <cstddef>

#define NN 50000
#define NE 800000
#define RREL 5
#define NR (NN * RREL)                 // 250000 (dst,type) keys
#define NB5 ((NR + 255) / 256)         // 977

typedef __attribute__((ext_vector_type(8))) short short8;   // 8 bf16 (4 VGPRs)
typedef __attribute__((ext_vector_type(4))) float f32x4;

static __device__ __forceinline__ float lrelu(float v) { return v > 0.f ? v : 0.01f * v; }

static __device__ __forceinline__ unsigned short f32_bf16_rn(float x) {
    unsigned u = __float_as_uint(x);
    return (unsigned short)((u + 0x7FFFu + ((u >> 16) & 1u)) >> 16);
}

// split 8 f32 (two float4) into bf16 hi + lo (x ~= hi + lo)
static __device__ __forceinline__ void split8v(float4 q0, float4 q1, short8& hi, short8& lo) {
    float v[8] = {q0.x, q0.y, q0.z, q0.w, q1.x, q1.y, q1.z, q1.w};
    #pragma unroll
    for (int j = 0; j < 8; ++j) {
        unsigned short h = f32_bf16_rn(v[j]);
        float hf = __uint_as_float(((unsigned)h) << 16);
        unsigned short l = f32_bf16_rn(v[j] - hf);
        hi[j] = (short)h; lo[j] = (short)l;
    }
}

// ---------------------------------------------------------------------------
// 64x64-tile f32 GEMM (e0 = x @ field_W + field_b, K=128)
// ---------------------------------------------------------------------------
template<int K>
__launch_bounds__(256)
__global__ void gemm_tile(const float* __restrict__ A, int lda,
                          const float* __restrict__ B0,
                          const float* __restrict__ bias,
                          float* __restrict__ C, int M)
{
    __shared__ float As[64][68];
    __shared__ float Bs[64][64];
    const int row0 = blockIdx.x * 64;
    const int t = threadIdx.x;
    const int tx = t & 15, ty = t >> 4;

    float acc[4][4] = {};

    for (int kc = 0; kc < K; kc += 64) {
        {
            int arow = t >> 4, akk = (t & 15) << 2;
            #pragma unroll
            for (int rp = 0; rp < 64; rp += 16) {
                int r = rp + arow, gr = row0 + r;
                float4 v = make_float4(0.f, 0.f, 0.f, 0.f);
                if (gr < M) v = *(const float4*)&A[(size_t)gr * lda + kc + akk];
                As[akk + 0][r] = v.x; As[akk + 1][r] = v.y;
                As[akk + 2][r] = v.z; As[akk + 3][r] = v.w;
            }
        }
        #pragma unroll
        for (int idx = t; idx < 1024; idx += 256) {
            int k = idx >> 4, c4 = (idx & 15) << 2;
            *(float4*)&Bs[k][c4] = *(const float4*)&B0[(size_t)(kc + k) * 64 + c4];
        }
        __syncthreads();

        #pragma unroll 8
        for (int k = 0; k < 64; ++k) {
            float4 av = *(const float4*)&As[k][ty * 4];
            float4 bv = *(const float4*)&Bs[k][tx * 4];
            float ar[4] = {av.x, av.y, av.z, av.w};
            float br[4] = {bv.x, bv.y, bv.z, bv.w};
            #pragma unroll
            for (int i = 0; i < 4; ++i)
                #pragma unroll
                for (int j = 0; j < 4; ++j)
                    acc[i][j] = fmaf(ar[i], br[j], acc[i][j]);
        }
        __syncthreads();
    }

    float bb[4];
    {
        const float* bp = bias + tx * 4;
        bb[0] = bp[0]; bb[1] = bp[1]; bb[2] = bp[2]; bb[3] = bp[3];
    }
    #pragma unroll
    for (int i = 0; i < 4; ++i) {
        int gr = row0 + ty * 4 + i;
        if (gr >= M) continue;
        *(float4*)&C[(size_t)gr * 64 + tx * 4] =
            make_float4(acc[i][0] + bb[0], acc[i][1] + bb[1],
                        acc[i][2] + bb[2], acc[i][3] + bb[3]);
    }
}

// ---------------------------------------------------------------------------
// zgather v3: one wave per dst node, full-range 4-deep pipelined walk with
// wave-uniform segment flushes (type-grouped CSR; boundaries are scalars).
// ---------------------------------------------------------------------------
__launch_bounds__(256)
__global__ void zgather(const int* __restrict__ offs5, const uint2* __restrict__ epack,
                        const float* __restrict__ Eprev,
                        float* __restrict__ Z, float* __restrict__ S)
{
    int wid = (blockIdx.x * 256 + threadIdx.x) >> 6;
    int lane = threadIdx.x & 63;
    if (wid >= NN) return;
    const int b = wid * RREL;

    // boundaries (shift-register, all static)
    int p    = offs5[b];
    int n1   = offs5[b + 1];
    int n2   = offs5[b + 2];
    int n3   = offs5[b + 3];
    int n4   = offs5[b + 4];
    int pend = offs5[b + 5];

    float* zr = Z + (size_t)wid * 320 + lane;
    const int INFP = 0x7fffffff;

    int r = 0;
    float zacc = 0.f, zacc2 = 0.f, sacc = 0.f, sacc2 = 0.f;

    // flush helper expanded inline (r advances; boundary regs shift)
#define FLUSH_CHECK(pe)                                                     \
    while (r < 4 && (pe) == n1) {                                           \
        zr[(size_t)(r << 6)] = zacc + zacc2;                                \
        if (lane == 0) S[b + r] = sacc + sacc2;                             \
        zacc = 0.f; zacc2 = 0.f; sacc = 0.f; sacc2 = 0.f;                   \
        ++r; n1 = n2; n2 = n3; n3 = n4; n4 = INFP;                          \
    }

    for (; p + 4 <= pend; p += 4) {
        uint2 q0 = epack[p + 0], q1 = epack[p + 1];
        uint2 q2 = epack[p + 2], q3 = epack[p + 3];
        float v0 = Eprev[(size_t)q0.x * 64 + lane];
        float v1 = Eprev[(size_t)q1.x * 64 + lane];
        float v2 = Eprev[(size_t)q2.x * 64 + lane];
        float v3 = Eprev[(size_t)q3.x * 64 + lane];

        FLUSH_CHECK(p + 0);
        zacc  = fmaf(__uint_as_float(q0.y), v0, zacc);  sacc  += __uint_as_float(q0.y);
        FLUSH_CHECK(p + 1);
        zacc2 = fmaf(__uint_as_float(q1.y), v1, zacc2); sacc2 += __uint_as_float(q1.y);
        FLUSH_CHECK(p + 2);
        zacc  = fmaf(__uint_as_float(q2.y), v2, zacc);  sacc  += __uint_as_float(q2.y);
        FLUSH_CHECK(p + 3);
        zacc2 = fmaf(__uint_as_float(q3.y), v3, zacc2); sacc2 += __uint_as_float(q3.y);
    }
    for (; p < pend; ++p) {
        uint2 q = epack[p];
        float v = Eprev[(size_t)q.x * 64 + lane];
        FLUSH_CHECK(p);
        zacc = fmaf(__uint_as_float(q.y), v, zacc);
        sacc += __uint_as_float(q.y);
    }
    // final flushes (current segment + any trailing empty segments)
    while (r < RREL) {
        zr[(size_t)(r << 6)] = zacc + zacc2;
        if (lane == 0) S[b + r] = sacc + sacc2;
        zacc = 0.f; zacc2 = 0.f; sacc = 0.f; sacc2 = 0.f;
        ++r;
    }
#undef FLUSH_CHECK
}

// ---------------------------------------------------------------------------
// prep_wfrag: relW [R][128][64] f32 -> split-bf16 MFMA fragments.
// ---------------------------------------------------------------------------
__launch_bounds__(256)
__global__ void prep_wfrag(const float* __restrict__ rel1_W, const float* __restrict__ rel2_W,
                           short8* __restrict__ wf1, short8* __restrict__ wf2)
{
    int bid = blockIdx.x;
    int layer = bid / 10, c = bid % 10;
    const float* relW = layer ? rel2_W : rel1_W;
    short8* wf = layer ? wf2 : wf1;
    int t = threadIdx.x;
    for (int sl = t; sl < 512; sl += 256) {
        int rid = sl >> 6, lane = sl & 63;
        int s = rid >> 2, nf = rid & 3;
        int g = lane >> 4, lc = lane & 15;
        int r = (c < 5) ? c : c - 5;
        const float* W = relW + (size_t)r * 8192 + ((c < 5) ? 0 : 4096);
        float v[8];
        #pragma unroll
        for (int j = 0; j < 8; ++j)
            v[j] = W[(size_t)(s * 32 + g * 8 + j) * 64 + nf * 16 + lc];
        float4 q0 = make_float4(v[0], v[1], v[2], v[3]);
        float4 q1 = make_float4(v[4], v[5], v[6], v[7]);
        short8 hi, lo;
        split8v(q0, q1, hi, lo);
        size_t slot = (size_t)c * 1024 + (size_t)((s * 4 + nf) * 64 + lane) * 2;
        wf[slot]     = hi;
        wf[slot + 1] = lo;
    }
}

// ---------------------------------------------------------------------------
// zgemm_mfma: 2-phase LDS pipeline (unchanged).
// ---------------------------------------------------------------------------
__launch_bounds__(512)
__global__ void zgemm_mfma(const float* __restrict__ Z,
                           const float* __restrict__ Eprev,
                           const short8* __restrict__ wf,
                           const float* __restrict__ relb,
                           const float* __restrict__ S,
                           float* __restrict__ Enext, int M)
{
    __shared__ short8 wlds[2][1024];   // 2 x 16 KB

    const int t = threadIdx.x;
    const int wid = t >> 6, lane = t & 63;
    const int lc = lane & 15, lg = lane >> 4;
    const int row0 = blockIdx.x * 128 + wid * 16;

    const int nA = row0 + lc;
    const bool okA = (nA < M);
    const int nodeA = okA ? nA : 0;

    const int sq = t >> 6, sl = t & 63;
    const int wrA = (sq * 2 + 0) * 64 + sl;
    const int wrB = (sq * 2 + 1) * 64 + sl;

    short8 eh[2], el[2];
    #pragma unroll
    for (int s = 0; s < 2; ++s) {
        const float* p = &Eprev[(size_t)nodeA * 64 + s * 32 + lg * 8];
        float4 q0 = okA ? *(const float4*)p       : make_float4(0,0,0,0);
        float4 q1 = okA ? *(const float4*)(p + 4) : make_float4(0,0,0,0);
        split8v(q0, q1, eh[s], el[s]);
    }

    float sD[4][RREL];
    #pragma unroll
    for (int i = 0; i < 4; ++i) {
        int nd = row0 + lg * 4 + i;
        int ns = (nd < M) ? nd : 0;
        #pragma unroll
        for (int r = 0; r < RREL; ++r)
            sD[i][r] = S[(size_t)ns * RREL + r];
    }

    {
        const short8* wp = wf + (size_t)t * 2;
        short8 sa = wp[0], sb = wp[1];
        wlds[0][wrA] = sa; wlds[0][wrB] = sb;
    }
    float4 az0[2], az1[2];
    {
        const float* p0 = &Z[(size_t)nodeA * 320 + 0 * 32 + lg * 8];
        const float* p1 = &Z[(size_t)nodeA * 320 + 1 * 32 + lg * 8];
        az0[0] = okA ? *(const float4*)p0       : make_float4(0,0,0,0);
        az0[1] = okA ? *(const float4*)(p0 + 4) : make_float4(0,0,0,0);
        az1[0] = okA ? *(const float4*)p1       : make_float4(0,0,0,0);
        az1[1] = okA ? *(const float4*)(p1 + 4) : make_float4(0,0,0,0);
    }
    __syncthreads();

    f32x4 acc[4];
    #pragma unroll
    for (int nf = 0; nf < 4; ++nf) acc[nf] = (f32x4){0.f, 0.f, 0.f, 0.f};

    short8 sreg_a, sreg_b;
    float4 pz0[2], pz1[2];

    #pragma unroll
    for (int c = 0; c < 10; ++c) {
        const int cb = c & 1;
        if (c < 9) {
            const short8* wp = wf + (size_t)(c + 1) * 1024 + (size_t)t * 2;
            sreg_a = wp[0]; sreg_b = wp[1];
        }
        if (c < 4) {
            const float* p0 = &Z[(size_t)nodeA * 320 + (c + 1) * 64 + 0 * 32 + lg * 8];
            const float* p1 = &Z[(size_t)nodeA * 320 + (c + 1) * 64 + 1 * 32 + lg * 8];
            pz0[0] = okA ? *(const float4*)p0       : make_float4(0,0,0,0);
            pz0[1] = okA ? *(const float4*)(p0 + 4) : make_float4(0,0,0,0);
            pz1[0] = okA ? *(const float4*)p1       : make_float4(0,0,0,0);
            pz1[1] = okA ? *(const float4*)(p1 + 4) : make_float4(0,0,0,0);
        }

        short8 Ah[2], Al[2];
        if (c < 5) {
            split8v(az0[0], az0[1], Ah[0], Al[0]);
            split8v(az1[0], az1[1], Ah[1], Al[1]);
        } else {
            Ah[0] = eh[0]; Al[0] = el[0];
            Ah[1] = eh[1]; Al[1] = el[1];
        }

        if (c < 5) {
            #pragma unroll
            for (int s = 0; s < 2; ++s)
                #pragma unroll
                for (int nf = 0; nf < 4; ++nf) {
                    short8 bh = wlds[cb][((s * 4 + nf) * 2 + 0) * 64 + lane];
                    short8 bl = wlds[cb][((s * 4 + nf) * 2 + 1) * 64 + lane];
                    acc[nf] = __builtin_amdgcn_mfma_f32_16x16x32_bf16(Ah[s], bh, acc[nf], 0, 0, 0);
                    acc[nf] = __builtin_amdgcn_mfma_f32_16x16x32_bf16(Al[s], bh, acc[nf], 0, 0, 0);
                    acc[nf] = __builtin_amdgcn_mfma_f32_16x16x32_bf16(Ah[s], bl, acc[nf], 0, 0, 0);
                }
        } else {
            f32x4 tmp[4];
            #pragma unroll
            for (int nf = 0; nf < 4; ++nf) tmp[nf] = (f32x4){0.f, 0.f, 0.f, 0.f};
            #pragma unroll
            for (int s = 0; s < 2; ++s)
                #pragma unroll
                for (int nf = 0; nf < 4; ++nf) {
                    short8 bh = wlds[cb][((s * 4 + nf) * 2 + 0) * 64 + lane];
                    short8 bl = wlds[cb][((s * 4 + nf) * 2 + 1) * 64 + lane];
                    tmp[nf] = __builtin_amdgcn_mfma_f32_16x16x32_bf16(Ah[s], bh, tmp[nf], 0, 0, 0);
                    tmp[nf] = __builtin_amdgcn_mfma_f32_16x16x32_bf16(Al[s], bh, tmp[nf], 0, 0, 0);
                    tmp[nf] = __builtin_amdgcn_mfma_f32_16x16x32_bf16(Ah[s], bl, tmp[nf], 0, 0, 0);
                }
            const int r = c - 5;
            #pragma unroll
            for (int nf = 0; nf < 4; ++nf)
                #pragma unroll
                for (int i = 0; i < 4; ++i)
                    acc[nf][i] += sD[i][r] * tmp[nf][i];
        }

        if (c < 4) {
            az0[0] = pz0[0]; az0[1] = pz0[1];
            az1[0] = pz1[0]; az1[1] = pz1[1];
        }

        if (c < 9) {
            __syncthreads();
            wlds[cb ^ 1][wrA] = sreg_a;
            wlds[cb ^ 1][wrB] = sreg_b;
            __syncthreads();
        }
    }

    float bbv[4][RREL];
    #pragma unroll
    for (int nf = 0; nf < 4; ++nf)
        #pragma unroll
        for (int r = 0; r < RREL; ++r)
            bbv[nf][r] = relb[r * 64 + nf * 16 + lc];

    #pragma unroll
    for (int i = 0; i < 4; ++i) {
        int nd = row0 + lg * 4 + i;
        if (nd >= M) continue;
        #pragma unroll
        for (int nf = 0; nf < 4; ++nf) {
            float v = acc[nf][i];
            #pragma unroll
            for (int r = 0; r < RREL; ++r)
                v += sD[i][r] * bbv[nf][r];
            Enext[(size_t)nd * 64 + nf * 16 + lc] = v;
        }
    }
}

// ---------------------------------------------------------------------------
// Fused output head: out = sum_s lrelu(Es @ Ws + bs)
// ---------------------------------------------------------------------------
__launch_bounds__(256)
__global__ void head_fused(const float* __restrict__ E0, const float* __restrict__ E1,
                           const float* __restrict__ E2,
                           const float* __restrict__ W0, const float* __restrict__ W1,
                           const float* __restrict__ W2,
                           const float* __restrict__ b0, const float* __restrict__ b1,
                           const float* __restrict__ b2,
                           float* __restrict__ out, int M)
{
    __shared__ float As[64][68];
    __shared__ float Bs[64][64];
    const int row0 = blockIdx.x * 64;
    const int t = threadIdx.x;
    const int tx = t & 15, ty = t >> 4;

    const float* Es[3] = {E0, E1, E2};
    const float* Ws[3] = {W0, W1, W2};
    const float* bs[3] = {b0, b1, b2};

    float acc[4][4] = {};

    #pragma unroll
    for (int s = 0; s < 3; ++s) {
        __syncthreads();
        {
            int arow = t >> 4, akk = (t & 15) << 2;
            #pragma unroll
            for (int rp = 0; rp < 64; rp += 16) {
                int r = rp + arow, gr = row0 + r;
                float4 v = make_float4(0.f, 0.f, 0.f, 0.f);
                if (gr < M) v = *(const float4*)&Es[s][(size_t)gr * 64 + akk];
                As[akk + 0][r] = v.x; As[akk + 1][r] = v.y;
                As[akk + 2][r] = v.z; As[akk + 3][r] = v.w;
            }
        }
        #pragma unroll
        for (int idx = t; idx < 1024; idx += 256) {
            int k = idx >> 4, c4 = (idx & 15) << 2;
            *(float4*)&Bs[k][c4] = *(const float4*)&Ws[s][(size_t)k * 64 + c4];
        }
        __syncthreads();

        float tmp[4][4] = {};
        #pragma unroll 8
        for (int k = 0; k < 64; ++k) {
            float4 av = *(const float4*)&As[k][ty * 4];
            float4 bv = *(const float4*)&Bs[k][tx * 4];
            float ar[4] = {av.x, av.y, av.z, av.w};
            float br[4] = {bv.x, bv.y, bv.z, bv.w};
            #pragma unroll
            for (int i = 0; i < 4; ++i)
                #pragma unroll
                for (int j = 0; j < 4; ++j)
                    tmp[i][j] = fmaf(ar[i], br[j], tmp[i][j]);
        }
        float bb[4];
        {
            const float* bp = bs[s] + tx * 4;
            bb[0] = bp[0]; bb[1] = bp[1]; bb[2] = bp[2]; bb[3] = bp[3];
        }
        #pragma unroll
        for (int i = 0; i < 4; ++i)
            #pragma unroll
            for (int j = 0; j < 4; ++j)
                acc[i][j] += lrelu(tmp[i][j] + bb[j]);
    }

    #pragma unroll
    for (int i = 0; i < 4; ++i) {
        int gr = row0 + ty * 4 + i;
        if (gr >= M) continue;
        *(float4*)&out[(size_t)gr * 64 + tx * 4] =
            make_float4(acc[i][0], acc[i][1], acc[i][2], acc[i][3]);
    }
}

// ---------------------------------------------------------------------------
// CSR build over (dst,type) keys
// ---------------------------------------------------------------------------
__launch_bounds__(256)
__global__ void deg5_hist(const int* __restrict__ dst, const int* __restrict__ etype,
                          int* __restrict__ deg5, int* __restrict__ slot5)
{
    int e = blockIdx.x * 256 + threadIdx.x;
    if (e < NE) slot5[e] = atomicAdd(&deg5[dst[e] * RREL + etype[e]], 1);
}

__launch_bounds__(256)
__global__ void b1_reduce(const int* __restrict__ deg5, int* __restrict__ b1)
{
    __shared__ int sh[256];
    int i = blockIdx.x * 256 + threadIdx.x;
    sh[threadIdx.x] = (i < NR) ? deg5[i] : 0;
    __syncthreads();
    for (int s = 128; s > 0; s >>= 1) {
        if (threadIdx.x < s) sh[threadIdx.x] += sh[threadIdx.x + s];
        __syncthreads();
    }
    if (threadIdx.x == 0) b1[blockIdx.x] = sh[0];
}

__launch_bounds__(256)
__global__ void scan_seq(int* __restrict__ b1, int n)
{
    __shared__ int sh[256];
    __shared__ int carry;
    if (threadIdx.x == 0) carry = 0;
    __syncthreads();
    for (int base = 0; base < n; base += 256) {
        int i = base + threadIdx.x;
        int v = (i < n) ? b1[i] : 0;
        sh[threadIdx.x] = v;
        __syncthreads();
        for (int off = 1; off < 256; off <<= 1) {
            int x = (threadIdx.x >= off) ? sh[threadIdx.x - off] : 0;
            __syncthreads();
            sh[threadIdx.x] += x;
            __syncthreads();
        }
        int excl = sh[threadIdx.x] - v + carry;
        if (i < n) b1[i] = excl;
        __syncthreads();
        if (threadIdx.x == 255) carry = excl + v;
        __syncthreads();
    }
}

__launch_bounds__(256)
__global__ void offs5_final(const int* __restrict__ deg5, const int* __restrict__ b1,
                            int* __restrict__ offs5)
{
    __shared__ int sh[256];
    int t = threadIdx.x;
    int i = blockIdx.x * 256 + t;
    int v = (i < NR) ? deg5[i] : 0;
    sh[t] = v;
    __syncthreads();
    for (int off = 1; off < 256; off <<= 1) {
        int x = (t >= off) ? sh[t - off] : 0;
        __syncthreads();
        sh[t] += x;
        __syncthreads();
    }
    int excl = sh[t] - v + b1[blockIdx.x];
    if (i <= NR) offs5[i] = excl;
}

// scatter: epack[offs5[dst*5+r] + slot5[e]] = {src, w}
__launch_bounds__(256)
__global__ void scatter_pass(const int* __restrict__ src, const int* __restrict__ dst,
                             const int* __restrict__ etype,
                             const float* __restrict__ etime,
                             const float* __restrict__ beta,
                             const float* __restrict__ lambda_p,
                             const int* __restrict__ slot5, const int* __restrict__ offs5,
                             uint2* __restrict__ epack)
{
    int e = blockIdx.x * 256 + threadIdx.x;
    if (e >= NE) return;
    float b[12];
    #pragma unroll
    for (int j = 0; j < 12; ++j) b[j] = beta[j];
    const float* et = etime + (size_t)e * 12;
    float4 v0 = *(const float4*)(et);
    float4 v1 = *(const float4*)(et + 4);
    float4 v2 = *(const float4*)(et + 8);
    float logit = v0.x*b[0] + v0.y*b[1] + v0.z*b[2] + v0.w*b[3]
                + v1.x*b[4] + v1.y*b[5] + v1.z*b[6] + v1.w*b[7]
                + v2.x*b[8] + v2.y*b[9] + v2.z*b[10] + v2.w*b[11];
    float we = lambda_p[0] * expf(-logit);
    int p = offs5[dst[e] * RREL + etype[e]] + slot5[e];
    epack[p] = make_uint2((unsigned)src[e], __float_as_uint(we));
}

// ---------------------------------------------------------------------------
extern "C" void kernel_launch(void* const* d_in, const int* in_sizes, int n_in,
                              void* d_out, int out_size, void* d_ws, size_t ws_size,
                              hipStream_t stream)
{
    const float* x        = (const float*)d_in[0];
    const int*   eidx     = (const int*)d_in[1];
    const int*   etype    = (const int*)d_in[2];
    const float* etime    = (const float*)d_in[3];
    const float* lambda_p = (const float*)d_in[4];
    const float* beta     = (const float*)d_in[5];
    const float* field_W  = (const float*)d_in[6];
    const float* field_b  = (const float*)d_in[7];
    const float* rel1_W   = (const float*)d_in[8];
    const float* rel1_b   = (const float*)d_in[9];
    const float* rel2_W   = (const float*)d_in[10];
    const float* rel2_b   = (const float*)d_in[11];
    const float* out0_W   = (const float*)d_in[12];
    const float* out0_b   = (const float*)d_in[13];
    const float* out1_W   = (const float*)d_in[14];
    const float* out1_b   = (const float*)d_in[15];
    const float* out2_W   = (const float*)d_in[16];
    const float* out2_b   = (const float*)d_in[17];
    const int* src = eidx;
    const int* dst = eidx + NE;
    float* out = (float*)d_out;

    char* wsb = (char*)d_ws;
    size_t off = 0;
    auto carve = [&](size_t bytes) -> void* {
        void* p = (void*)(wsb + off);
        off += (bytes + 255) & ~(size_t)255;
        return p;
    };
    int*   deg5   = (int*)carve((size_t)NR * 4);            // 1 MB
    int*   offs5  = (int*)carve((size_t)(NR + 1) * 4);      // 1 MB
    int*   b1     = (int*)carve((size_t)NB5 * 4);
    int*   slot5  = (int*)carve((size_t)NE * 4);            // 3.2 MB
    float* S      = (float*)carve((size_t)NR * 4);          // 1 MB
    uint2* epack  = (uint2*)carve((size_t)NE * 8);          // 6.4 MB
    float* e0     = (float*)carve((size_t)NN * 64 * 4);     // 12.8 MB
    float* e1     = (float*)carve((size_t)NN * 64 * 4);     // 12.8 MB
    float* e2     = (float*)carve((size_t)NN * 64 * 4);     // 12.8 MB
    float* Zb     = (float*)carve((size_t)NN * 320 * 4);    // 64 MB
    short8* wf1   = (short8*)carve((size_t)20 * 16384);     // 320 KB
    short8* wf2   = (short8*)carve((size_t)20 * 16384);     // 320 KB

    dim3 blk(256);
    const int NT64  = (NN + 63) / 64;       // 782
    const int NT128 = (NN + 127) / 128;     // 391
    const int EB = (NE + 255) / 256;
    const int GB = (NN * 64 + 255) / 256;   // one wave per node

    // ---- CSR build over (dst,type) + weight frag prep ----
    hipMemsetAsync(deg5, 0, (size_t)NR * 4, stream);
    deg5_hist<<<EB, blk, 0, stream>>>(dst, etype, deg5, slot5);
    prep_wfrag<<<20, blk, 0, stream>>>(rel1_W, rel2_W, wf1, wf2);
    b1_reduce<<<NB5, blk, 0, stream>>>(deg5, b1);
    scan_seq<<<1, blk, 0, stream>>>(b1, NB5);
    offs5_final<<<NB5, blk, 0, stream>>>(deg5, b1, offs5);
    scatter_pass<<<EB, blk, 0, stream>>>(src, dst, etype, etime, beta, lambda_p,
                                         slot5, offs5, epack);

    // ---- e0 = x @ field_W + field_b ----
    gemm_tile<128><<<dim3(NT64), blk, 0, stream>>>(x, 128, field_W, field_b, e0, NN);

    // ---- layer 1 ----
    zgather<<<GB, blk, 0, stream>>>(offs5, epack, e0, Zb, S);
    zgemm_mfma<<<dim3(NT128), dim3(512), 0, stream>>>(Zb, e0, wf1, rel1_b, S, e1, NN);

    // ---- layer 2 ----
    zgather<<<GB, blk, 0, stream>>>(offs5, epack, e1, Zb, S);
    zgemm_mfma<<<dim3(NT128), dim3(512), 0, stream>>>(Zb, e1, wf2, rel2_b, S, e2, NN);

    // ---- output head (single pass) ----
    head_fused<<<dim3(NT64), blk, 0, stream>>>(e0, e1, e2, out0_W, out1_W, out2_W,
                                               out0_b, out1_b, out2_b, out, NN);
}